// Round 3
// baseline (1222.490 us; speedup 1.0000x reference)
//
#include <hip/hip_runtime.h>
#include <math.h>

#define NN 100000
#define NE 3200000
#define BSH 8
#define BSZ 256                       // dst-nodes per bucket
#define NBKT 391                      // ceil(NN / BSZ)
#define TILE 4096
#define NTB 782                       // ceil(NE / TILE)

#define FMA4(a, s, v) { (a).x += (s)*(v).x; (a).y += (s)*(v).y; (a).z += (s)*(v).z; (a).w += (s)*(v).w; }

// ---------------- bucket histogram (391 buckets, LDS-aggregated)
__global__ __launch_bounds__(256) void bhist_k(const int* __restrict__ ei, int* __restrict__ bhist) {
    __shared__ int h[NBKT];
    int t = threadIdx.x;
    for (int j = t; j < NBKT; j += 256) h[j] = 0;
    __syncthreads();
    int e0 = blockIdx.x * TILE + t;
    #pragma unroll
    for (int i = 0; i < 16; i++) {
        int e = e0 + i * 256;
        if (e < NE) atomicAdd(&h[ei[NE + e] >> BSH], 1);
    }
    __syncthreads();
    for (int j = t; j < NBKT; j += 256) if (h[j]) atomicAdd(&bhist[j], h[j]);
}

// ---------------- scan 391 bucket counts -> offsets + cursors (1 block)
__global__ __launch_bounds__(512) void bscan_k(const int* __restrict__ bhist,
                                               int* __restrict__ boff, int* __restrict__ bcur) {
    __shared__ int s[512];
    int t = threadIdx.x;
    int v = (t < NBKT) ? bhist[t] : 0;
    s[t] = v;
    __syncthreads();
    #pragma unroll
    for (int ofs = 1; ofs < 512; ofs <<= 1) {
        int a = (t >= ofs) ? s[t - ofs] : 0;
        __syncthreads();
        s[t] += a;
        __syncthreads();
    }
    if (t < NBKT) { boff[t] = s[t] - v; bcur[t] = s[t] - v; }
}

// ---------------- bucket scatter: block-contiguous runs per bucket
__global__ __launch_bounds__(256) void bscatter_k(const int* __restrict__ ei, const float* __restrict__ ea,
                                                  int* __restrict__ bcur, int2* __restrict__ pk) {
    __shared__ int h[NBKT];
    __shared__ int base[NBKT];
    int t = threadIdx.x;
    for (int j = t; j < NBKT; j += 256) h[j] = 0;
    __syncthreads();
    int e0 = blockIdx.x * TILE + t;
    int pck[16], bk[16], rk[16];
    float uu[16];
    #pragma unroll
    for (int i = 0; i < 16; i++) {
        int e = e0 + i * 256;
        bk[i] = -1;
        if (e < NE) {
            int s = ei[e];
            int d = ei[NE + e];
            uu[i] = fminf(fmaxf(ea[e], 0.f), 1.f);
            bk[i] = d >> BSH;
            pck[i] = (s << BSH) | (d & (BSZ - 1));     // src 17b | dst-local 8b
            rk[i] = atomicAdd(&h[bk[i]], 1);
        }
    }
    __syncthreads();
    for (int j = t; j < NBKT; j += 256) base[j] = h[j] ? atomicAdd(&bcur[j], h[j]) : 0;
    __syncthreads();
    #pragma unroll
    for (int i = 0; i < 16; i++)
        if (bk[i] >= 0) pk[base[bk[i]] + rk[i]] = make_int2(pck[i], __float_as_int(uu[i]));
}

// ---------------- layer-1 node transform: y01 interleaved [n][ y0(32) | y1(32) ], xr
__global__ __launch_bounds__(256) void transform1_k(
    const float* __restrict__ x, const float* __restrict__ W, const float* __restrict__ R,
    float* __restrict__ y01, float* __restrict__ xr)
{
    __shared__ float W0s[1024], W1s[1024], Rs[1024];
    __shared__ float xs[32 * 33];
    int tid = threadIdx.x;
    for (int i = tid; i < 1024; i += 256) {
        W0s[i] = W[i];
        W1s[i] = W[1024 + i];
        Rs[i]  = R[i];
    }
    int nb = blockIdx.x * 32;
    for (int i = tid; i < 1024; i += 256) {
        int n = nb + (i >> 5);
        xs[(i >> 5) * 33 + (i & 31)] = (n < NN) ? x[n * 32 + (i & 31)] : 0.f;
    }
    __syncthreads();
    int local = tid >> 3, c = tid & 7;
    int n = nb + local;
    float4 a0 = make_float4(0.f, 0.f, 0.f, 0.f), a1 = a0, a2 = a0;
    #pragma unroll
    for (int k = 0; k < 32; k++) {
        float xk = xs[local * 33 + k];
        float4 w0 = ((const float4*)W0s)[k * 8 + c];
        float4 w1 = ((const float4*)W1s)[k * 8 + c];
        float4 r  = ((const float4*)Rs)[k * 8 + c];
        FMA4(a0, xk, w0); FMA4(a1, xk, w1); FMA4(a2, xk, r);
    }
    if (n < NN) {
        ((float4*)y01)[n * 16 + c]     = a0;
        ((float4*)y01)[n * 16 + 8 + c] = a1;
        ((float4*)xr)[n * 8 + c]       = a2;
    }
}

// ---------------- layer-1 bucket aggregate (LDS acc) + mean + root + bias + relu
__global__ __launch_bounds__(256) void agg1_k(
    const int* __restrict__ boff, const int* __restrict__ bhist, const int2* __restrict__ pk,
    const float* __restrict__ y01, const float* __restrict__ b, float* __restrict__ hx)
{
    __shared__ float acc[BSZ * 33];    // +1 pad per row: feature bank shift
    __shared__ int cnt[BSZ];
    int t = threadIdx.x;
    for (int j = t; j < BSZ * 33; j += 256) acc[j] = 0.f;
    for (int j = t; j < BSZ; j += 256) cnt[j] = 0;
    __syncthreads();
    int bkt = blockIdx.x;
    int st = boff[bkt], ne = bhist[bkt];
    int c = t & 7;
    const float4* y4 = (const float4*)y01;
    for (int i = t >> 3; i < ne; i += 32) {      // 8 lanes/edge, 32 edges in flight
        int2 p = pk[st + i];
        int s  = p.x >> BSH;
        int dl = p.x & (BSZ - 1);
        float u = __int_as_float(p.y);
        float4 a  = y4[(size_t)s * 16 + c];
        float4 bb = y4[(size_t)s * 16 + 8 + c];
        float* ap = &acc[dl * 33 + c * 4];
        atomicAdd(ap + 0, a.x + u * (bb.x - a.x));
        atomicAdd(ap + 1, a.y + u * (bb.y - a.y));
        atomicAdd(ap + 2, a.z + u * (bb.z - a.z));
        atomicAdd(ap + 3, a.w + u * (bb.w - a.w));
        if (c == 0) atomicAdd(&cnt[dl], 1);
    }
    __syncthreads();
    int nb = bkt * BSZ;
    for (int r0 = 0; r0 < BSZ; r0 += 8) {
        int row = r0 + (t >> 5), f = t & 31;
        int n = nb + row;
        if (n < NN) {
            float inv = 1.f / fmaxf((float)cnt[row], 1.f);
            float v = acc[row * 33 + f] * inv + hx[n * 32 + f] + b[f];
            hx[n * 32 + f] = fmaxf(v, 0.f);
        }
    }
}

// ---------------- layer-2 node transform: z01 interleaved [n][ z0(16) | z1(16) ], hr
__global__ __launch_bounds__(256) void transform2_k(
    const float* __restrict__ h, const float* __restrict__ W, const float* __restrict__ R,
    float* __restrict__ z01, float* __restrict__ hr)
{
    __shared__ float W0s[512], W1s[512], Rs[512];
    __shared__ float xs[64 * 33];
    int tid = threadIdx.x;
    for (int i = tid; i < 512; i += 256) {
        W0s[i] = W[i];
        W1s[i] = W[512 + i];
        Rs[i]  = R[i];
    }
    int nb = blockIdx.x * 64;
    for (int i = tid; i < 2048; i += 256) {
        int n = nb + (i >> 5);
        xs[(i >> 5) * 33 + (i & 31)] = (n < NN) ? h[n * 32 + (i & 31)] : 0.f;
    }
    __syncthreads();
    int local = tid >> 2, c = tid & 3;
    int n = nb + local;
    float4 a0 = make_float4(0.f, 0.f, 0.f, 0.f), a1 = a0, a2 = a0;
    #pragma unroll
    for (int k = 0; k < 32; k++) {
        float xk = xs[local * 33 + k];
        float4 w0 = ((const float4*)W0s)[k * 4 + c];
        float4 w1 = ((const float4*)W1s)[k * 4 + c];
        float4 r  = ((const float4*)Rs)[k * 4 + c];
        FMA4(a0, xk, w0); FMA4(a1, xk, w1); FMA4(a2, xk, r);
    }
    if (n < NN) {
        ((float4*)z01)[n * 8 + c]     = a0;
        ((float4*)z01)[n * 8 + 4 + c] = a1;
        ((float4*)hr)[n * 4 + c]      = a2;
    }
}

// ---------------- layer-2 bucket aggregate + mean + root + bias + log_softmax
__global__ __launch_bounds__(256) void agg2_k(
    const int* __restrict__ boff, const int* __restrict__ bhist, const int2* __restrict__ pk,
    const float* __restrict__ z01, const float* __restrict__ hr, const float* __restrict__ b,
    float* __restrict__ out)
{
    __shared__ float acc[BSZ * 17];
    __shared__ int cnt[BSZ];
    int t = threadIdx.x;
    for (int j = t; j < BSZ * 17; j += 256) acc[j] = 0.f;
    for (int j = t; j < BSZ; j += 256) cnt[j] = 0;
    __syncthreads();
    int bkt = blockIdx.x;
    int st = boff[bkt], ne = bhist[bkt];
    int c = t & 3;
    const float4* z4 = (const float4*)z01;
    for (int i = t >> 2; i < ne; i += 64) {      // 4 lanes/edge, 64 edges in flight
        int2 p = pk[st + i];
        int s  = p.x >> BSH;
        int dl = p.x & (BSZ - 1);
        float u = __int_as_float(p.y);
        float4 a  = z4[(size_t)s * 8 + c];
        float4 bb = z4[(size_t)s * 8 + 4 + c];
        float* ap = &acc[dl * 17 + c * 4];
        atomicAdd(ap + 0, a.x + u * (bb.x - a.x));
        atomicAdd(ap + 1, a.y + u * (bb.y - a.y));
        atomicAdd(ap + 2, a.z + u * (bb.z - a.z));
        atomicAdd(ap + 3, a.w + u * (bb.w - a.w));
        if (c == 0) atomicAdd(&cnt[dl], 1);
    }
    __syncthreads();
    int nb = bkt * BSZ;
    for (int r0 = 0; r0 < BSZ; r0 += 16) {       // 16 nodes per pass, 16 lanes/node
        int row = r0 + (t >> 4), f = t & 15;
        int n = nb + row;
        if (n < NN) {                            // whole 16-lane group uniform in row
            float inv = 1.f / fmaxf((float)cnt[row], 1.f);
            float o = acc[row * 17 + f] * inv + hr[n * 16 + f] + b[f];
            float m = o;
            #pragma unroll
            for (int ofs = 8; ofs; ofs >>= 1) m = fmaxf(m, __shfl_xor(m, ofs, 16));
            float sm = expf(o - m);
            #pragma unroll
            for (int ofs = 8; ofs; ofs >>= 1) sm += __shfl_xor(sm, ofs, 16);
            out[n * 16 + f] = o - (m + logf(sm));
        }
    }
}

extern "C" void kernel_launch(void* const* d_in, const int* in_sizes, int n_in,
                              void* d_out, int out_size, void* d_ws, size_t ws_size,
                              hipStream_t stream) {
    const float* x     = (const float*)d_in[0];
    const int*   ei    = (const int*)d_in[1];
    const float* ea    = (const float*)d_in[2];
    const float* W1    = (const float*)d_in[3];
    const float* root1 = (const float*)d_in[4];
    const float* b1    = (const float*)d_in[5];
    const float* W2    = (const float*)d_in[6];
    const float* root2 = (const float*)d_in[7];
    const float* b2    = (const float*)d_in[8];
    float* out = (float*)d_out;

    float* ws = (float*)d_ws;
    int*  bhist = (int*)ws;                        // 512
    int*  boff  = bhist + 512;                     // 512
    int*  bcur  = boff + 512;                      // 512
    int2* pk    = (int2*)(ws + 1536);              // NE int2 (8B aligned)
    float* y01  = ws + 1536 + 2 * (size_t)NE;      // NN*64
    float* xr_h = y01 + (size_t)NN * 64;           // NN*32
    float* z01  = y01;                             // reuse (NN*32)
    float* hr   = y01 + (size_t)NN * 32;           // reuse (NN*16)

    hipMemsetAsync(bhist, 0, NBKT * sizeof(int), stream);

    bhist_k   <<<NTB, 256, 0, stream>>>(ei, bhist);
    bscan_k   <<<1, 512, 0, stream>>>(bhist, boff, bcur);
    bscatter_k<<<NTB, 256, 0, stream>>>(ei, ea, bcur, pk);

    transform1_k<<<(NN + 31) / 32, 256, 0, stream>>>(x, W1, root1, y01, xr_h);
    agg1_k<<<NBKT, 256, 0, stream>>>(boff, bhist, pk, y01, b1, xr_h);

    transform2_k<<<(NN + 63) / 64, 256, 0, stream>>>(xr_h, W2, root2, z01, hr);
    agg2_k<<<NBKT, 256, 0, stream>>>(boff, bhist, pk, z01, hr, b2, out);
}

// Round 4
// 1113.526 us; speedup vs baseline: 1.0979x; 1.0979x over previous
//
#include <hip/hip_runtime.h>
#include <math.h>

#define NN 100000
#define NE 3200000
#define BSH 6
#define BSZ 64                        // dst-nodes per bucket
#define NBKT 1563                     // ceil(NN / BSZ)
#define TILE 4096
#define NTB 782                       // ceil(NE / TILE)

#define FMA4(a, s, v) { (a).x += (s)*(v).x; (a).y += (s)*(v).y; (a).z += (s)*(v).z; (a).w += (s)*(v).w; }

// ---------------- bucket histogram (LDS-aggregated)
__global__ __launch_bounds__(256) void bhist_k(const int* __restrict__ ei, int* __restrict__ bhist) {
    __shared__ int h[NBKT];
    int t = threadIdx.x;
    for (int j = t; j < NBKT; j += 256) h[j] = 0;
    __syncthreads();
    int e0 = blockIdx.x * TILE + t;
    #pragma unroll
    for (int i = 0; i < 16; i++) {
        int e = e0 + i * 256;
        if (e < NE) atomicAdd(&h[ei[NE + e] >> BSH], 1);
    }
    __syncthreads();
    for (int j = t; j < NBKT; j += 256) if (h[j]) atomicAdd(&bhist[j], h[j]);
}

// ---------------- scan NBKT bucket counts -> offsets + cursors (1 block, 8 elems/thread)
__global__ __launch_bounds__(256) void bscan_k(const int* __restrict__ bhist,
                                               int* __restrict__ boff, int* __restrict__ bcur) {
    __shared__ int ps[256];
    int t = threadIdx.x;
    int v[8]; int sum = 0;
    #pragma unroll
    for (int i = 0; i < 8; i++) {
        int j = t * 8 + i;
        v[i] = (j < NBKT) ? bhist[j] : 0;
        sum += v[i];
    }
    ps[t] = sum;
    __syncthreads();
    for (int ofs = 1; ofs < 256; ofs <<= 1) {
        int a = (t >= ofs) ? ps[t - ofs] : 0;
        __syncthreads();
        ps[t] += a;
        __syncthreads();
    }
    int run = ps[t] - sum;
    #pragma unroll
    for (int i = 0; i < 8; i++) {
        int j = t * 8 + i;
        if (j < NBKT) { boff[j] = run; bcur[j] = run; }
        run += v[i];
    }
}

// ---------------- bucket scatter: block-contiguous runs per bucket
__global__ __launch_bounds__(256) void bscatter_k(const int* __restrict__ ei, const float* __restrict__ ea,
                                                  int* __restrict__ bcur, int2* __restrict__ pk) {
    __shared__ int h[NBKT];
    __shared__ int base[NBKT];
    int t = threadIdx.x;
    for (int j = t; j < NBKT; j += 256) h[j] = 0;
    __syncthreads();
    int e0 = blockIdx.x * TILE + t;
    int pck[16], bk[16], rk[16];
    float uu[16];
    #pragma unroll
    for (int i = 0; i < 16; i++) {
        int e = e0 + i * 256;
        bk[i] = -1;
        if (e < NE) {
            int s = ei[e];
            int d = ei[NE + e];
            uu[i] = fminf(fmaxf(ea[e], 0.f), 1.f);
            bk[i] = d >> BSH;
            pck[i] = (s << BSH) | (d & (BSZ - 1));     // src 17b | dst-local 6b
            rk[i] = atomicAdd(&h[bk[i]], 1);
        }
    }
    __syncthreads();
    for (int j = t; j < NBKT; j += 256) base[j] = h[j] ? atomicAdd(&bcur[j], h[j]) : 0;
    __syncthreads();
    #pragma unroll
    for (int i = 0; i < 16; i++)
        if (bk[i] >= 0) pk[base[bk[i]] + rk[i]] = make_int2(pck[i], __float_as_int(uu[i]));
}

// ---------------- layer-1 node transform: y01 interleaved [n][ y0(32) | y1(32) ], xr
__global__ __launch_bounds__(256) void transform1_k(
    const float* __restrict__ x, const float* __restrict__ W, const float* __restrict__ R,
    float* __restrict__ y01, float* __restrict__ xr)
{
    __shared__ float W0s[1024], W1s[1024], Rs[1024];
    __shared__ float xs[32 * 33];
    int tid = threadIdx.x;
    for (int i = tid; i < 1024; i += 256) {
        W0s[i] = W[i];
        W1s[i] = W[1024 + i];
        Rs[i]  = R[i];
    }
    int nb = blockIdx.x * 32;
    for (int i = tid; i < 1024; i += 256) {
        int n = nb + (i >> 5);
        xs[(i >> 5) * 33 + (i & 31)] = (n < NN) ? x[n * 32 + (i & 31)] : 0.f;
    }
    __syncthreads();
    int local = tid >> 3, c = tid & 7;
    int n = nb + local;
    float4 a0 = make_float4(0.f, 0.f, 0.f, 0.f), a1 = a0, a2 = a0;
    #pragma unroll
    for (int k = 0; k < 32; k++) {
        float xk = xs[local * 33 + k];
        float4 w0 = ((const float4*)W0s)[k * 8 + c];
        float4 w1 = ((const float4*)W1s)[k * 8 + c];
        float4 r  = ((const float4*)Rs)[k * 8 + c];
        FMA4(a0, xk, w0); FMA4(a1, xk, w1); FMA4(a2, xk, r);
    }
    if (n < NN) {
        ((float4*)y01)[n * 16 + c]     = a0;
        ((float4*)y01)[n * 16 + 8 + c] = a1;
        ((float4*)xr)[n * 8 + c]       = a2;
    }
}

// ---------------- layer-1 bucket aggregate (LDS acc, 2-stage pipelined) -> relu(h)
__global__ __launch_bounds__(256) void agg1_k(
    const int* __restrict__ boff, const int* __restrict__ bhist, const int2* __restrict__ pk,
    const float* __restrict__ y01, const float* __restrict__ b, float* __restrict__ hx)
{
    __shared__ float acc[BSZ * 33];
    __shared__ int cnt[BSZ];
    int t = threadIdx.x;
    for (int j = t; j < BSZ * 33; j += 256) acc[j] = 0.f;
    if (t < BSZ) cnt[t] = 0;
    __syncthreads();
    int bkt = blockIdx.x;
    int st = boff[bkt], ne = bhist[bkt];
    int c = t & 7, slot = t >> 3;                 // 8 lanes/edge, 32 edges in flight
    const float4* y4 = (const float4*)y01;

    int idx0 = slot;
    int2 p0 = (idx0 < ne) ? pk[st + idx0] : make_int2(-1, 0);
    float4 a0 = make_float4(0,0,0,0), b0 = a0;
    if (p0.x >= 0) {
        int s = p0.x >> BSH;
        a0 = y4[(size_t)s * 16 + c];
        b0 = y4[(size_t)s * 16 + 8 + c];
    }
    int idx1 = idx0 + 32;
    int2 p1 = (idx1 < ne) ? pk[st + idx1] : make_int2(-1, 0);

    while (true) {
        // stage B: issue gathers for p1
        float4 a1 = make_float4(0,0,0,0), b1 = a1;
        if (p1.x >= 0) {
            int s = p1.x >> BSH;
            a1 = y4[(size_t)s * 16 + c];
            b1 = y4[(size_t)s * 16 + 8 + c];
        }
        // stage A: load pk two ahead
        int idx2 = idx1 + 32;
        int2 p2 = (idx2 < ne) ? pk[st + idx2] : make_int2(-1, 0);
        // stage C: commit p0
        if (p0.x >= 0) {
            int dl = p0.x & (BSZ - 1);
            float u = __int_as_float(p0.y);
            float* ap = &acc[dl * 33 + c * 4];
            atomicAdd(ap + 0, a0.x + u * (b0.x - a0.x));
            atomicAdd(ap + 1, a0.y + u * (b0.y - a0.y));
            atomicAdd(ap + 2, a0.z + u * (b0.z - a0.z));
            atomicAdd(ap + 3, a0.w + u * (b0.w - a0.w));
            if (c == 0) atomicAdd(&cnt[dl], 1);
        }
        if (idx1 >= ne) break;
        p0 = p1; a0 = a1; b0 = b1;
        p1 = p2; idx1 = idx2;
    }
    __syncthreads();
    int nb = bkt * BSZ;
    for (int r0 = 0; r0 < BSZ; r0 += 8) {
        int row = r0 + (t >> 5), f = t & 31;
        int n = nb + row;
        if (n < NN) {
            float inv = 1.f / fmaxf((float)cnt[row], 1.f);
            float v = acc[row * 33 + f] * inv + hx[n * 32 + f] + b[f];
            hx[n * 32 + f] = fmaxf(v, 0.f);
        }
    }
}

// ---------------- layer-2 node transform: z01 interleaved [n][ z0(16) | z1(16) ], hr
__global__ __launch_bounds__(256) void transform2_k(
    const float* __restrict__ h, const float* __restrict__ W, const float* __restrict__ R,
    float* __restrict__ z01, float* __restrict__ hr)
{
    __shared__ float W0s[512], W1s[512], Rs[512];
    __shared__ float xs[64 * 33];
    int tid = threadIdx.x;
    for (int i = tid; i < 512; i += 256) {
        W0s[i] = W[i];
        W1s[i] = W[512 + i];
        Rs[i]  = R[i];
    }
    int nb = blockIdx.x * 64;
    for (int i = tid; i < 2048; i += 256) {
        int n = nb + (i >> 5);
        xs[(i >> 5) * 33 + (i & 31)] = (n < NN) ? h[n * 32 + (i & 31)] : 0.f;
    }
    __syncthreads();
    int local = tid >> 2, c = tid & 3;
    int n = nb + local;
    float4 a0 = make_float4(0.f, 0.f, 0.f, 0.f), a1 = a0, a2 = a0;
    #pragma unroll
    for (int k = 0; k < 32; k++) {
        float xk = xs[local * 33 + k];
        float4 w0 = ((const float4*)W0s)[k * 4 + c];
        float4 w1 = ((const float4*)W1s)[k * 4 + c];
        float4 r  = ((const float4*)Rs)[k * 4 + c];
        FMA4(a0, xk, w0); FMA4(a1, xk, w1); FMA4(a2, xk, r);
    }
    if (n < NN) {
        ((float4*)z01)[n * 8 + c]     = a0;
        ((float4*)z01)[n * 8 + 4 + c] = a1;
        ((float4*)hr)[n * 4 + c]      = a2;
    }
}

// ---------------- layer-2 bucket aggregate (pipelined) + log_softmax
__global__ __launch_bounds__(256) void agg2_k(
    const int* __restrict__ boff, const int* __restrict__ bhist, const int2* __restrict__ pk,
    const float* __restrict__ z01, const float* __restrict__ hr, const float* __restrict__ b,
    float* __restrict__ out)
{
    __shared__ float acc[BSZ * 17];
    __shared__ int cnt[BSZ];
    int t = threadIdx.x;
    for (int j = t; j < BSZ * 17; j += 256) acc[j] = 0.f;
    if (t < BSZ) cnt[t] = 0;
    __syncthreads();
    int bkt = blockIdx.x;
    int st = boff[bkt], ne = bhist[bkt];
    int c = t & 3, slot = t >> 2;                 // 4 lanes/edge, 64 edges in flight
    const float4* z4 = (const float4*)z01;

    int idx0 = slot;
    int2 p0 = (idx0 < ne) ? pk[st + idx0] : make_int2(-1, 0);
    float4 a0 = make_float4(0,0,0,0), b0 = a0;
    if (p0.x >= 0) {
        int s = p0.x >> BSH;
        a0 = z4[(size_t)s * 8 + c];
        b0 = z4[(size_t)s * 8 + 4 + c];
    }
    int idx1 = idx0 + 64;
    int2 p1 = (idx1 < ne) ? pk[st + idx1] : make_int2(-1, 0);

    while (true) {
        float4 a1 = make_float4(0,0,0,0), b1 = a1;
        if (p1.x >= 0) {
            int s = p1.x >> BSH;
            a1 = z4[(size_t)s * 8 + c];
            b1 = z4[(size_t)s * 8 + 4 + c];
        }
        int idx2 = idx1 + 64;
        int2 p2 = (idx2 < ne) ? pk[st + idx2] : make_int2(-1, 0);
        if (p0.x >= 0) {
            int dl = p0.x & (BSZ - 1);
            float u = __int_as_float(p0.y);
            float* ap = &acc[dl * 17 + c * 4];
            atomicAdd(ap + 0, a0.x + u * (b0.x - a0.x));
            atomicAdd(ap + 1, a0.y + u * (b0.y - a0.y));
            atomicAdd(ap + 2, a0.z + u * (b0.z - a0.z));
            atomicAdd(ap + 3, a0.w + u * (b0.w - a0.w));
            if (c == 0) atomicAdd(&cnt[dl], 1);
        }
        if (idx1 >= ne) break;
        p0 = p1; a0 = a1; b0 = b1;
        p1 = p2; idx1 = idx2;
    }
    __syncthreads();
    int nb = bkt * BSZ;
    for (int r0 = 0; r0 < BSZ; r0 += 16) {        // 16 nodes/pass, 16 lanes/node
        int row = r0 + (t >> 4), f = t & 15;
        int n = nb + row;
        if (n < NN) {
            float inv = 1.f / fmaxf((float)cnt[row], 1.f);
            float o = acc[row * 17 + f] * inv + hr[n * 16 + f] + b[f];
            float m = o;
            #pragma unroll
            for (int ofs = 8; ofs; ofs >>= 1) m = fmaxf(m, __shfl_xor(m, ofs, 16));
            float sm = expf(o - m);
            #pragma unroll
            for (int ofs = 8; ofs; ofs >>= 1) sm += __shfl_xor(sm, ofs, 16);
            out[n * 16 + f] = o - (m + logf(sm));
        }
    }
}

extern "C" void kernel_launch(void* const* d_in, const int* in_sizes, int n_in,
                              void* d_out, int out_size, void* d_ws, size_t ws_size,
                              hipStream_t stream) {
    const float* x     = (const float*)d_in[0];
    const int*   ei    = (const int*)d_in[1];
    const float* ea    = (const float*)d_in[2];
    const float* W1    = (const float*)d_in[3];
    const float* root1 = (const float*)d_in[4];
    const float* b1    = (const float*)d_in[5];
    const float* W2    = (const float*)d_in[6];
    const float* root2 = (const float*)d_in[7];
    const float* b2    = (const float*)d_in[8];
    float* out = (float*)d_out;

    float* ws = (float*)d_ws;
    int*  bhist = (int*)ws;                        // NBKT (pad to 2048)
    int*  boff  = bhist + 2048;
    int*  bcur  = boff + 2048;
    int2* pk    = (int2*)(ws + 6144);              // NE int2
    float* y01  = ws + 6144 + 2 * (size_t)NE;      // NN*64
    float* xr_h = y01 + (size_t)NN * 64;           // NN*32
    float* z01  = y01;                             // reuse (NN*32)
    float* hr   = y01 + (size_t)NN * 32;           // reuse (NN*16)

    hipMemsetAsync(bhist, 0, NBKT * sizeof(int), stream);

    bhist_k   <<<NTB, 256, 0, stream>>>(ei, bhist);
    bscan_k   <<<1, 256, 0, stream>>>(bhist, boff, bcur);
    bscatter_k<<<NTB, 256, 0, stream>>>(ei, ea, bcur, pk);

    transform1_k<<<(NN + 31) / 32, 256, 0, stream>>>(x, W1, root1, y01, xr_h);
    agg1_k<<<NBKT, 256, 0, stream>>>(boff, bhist, pk, y01, b1, xr_h);

    transform2_k<<<(NN + 63) / 64, 256, 0, stream>>>(xr_h, W2, root2, z01, hr);
    agg2_k<<<NBKT, 256, 0, stream>>>(boff, bhist, pk, z01, hr, b2, out);
}